// Round 18
// baseline (999.524 us; speedup 1.0000x reference)
//
#include <hip/hip_runtime.h>
#include <math.h>

// ---------------------------------------------------------------------------
// VQ-VAE forward, bf16x3-MFMA for conv2, convT2 AND VQ distances.
//  x (32,1,256,256) -> h_pk (u32 hi|lo) -> z (f32) -> VQ -> q_pk (u32 hi|lo)
//  -> g (bf16 ushort, aliases h_pk) -> x_recon (32,1,256,256)
// d_out: [0]=vq_loss, [1..131072]=idx (as float), [131073..]=x_recon
// Fragment conventions (HW-verified, absmax 0.0 rounds 4-17):
//   A/B: lane l holds k_local = 8*(l>>4)+j, m/n = l&15
//   C/D: row = (l>>4)*4 + reg, col = l&15
// Round 18: g stored as plain bf16 (RNE) — dconv2 writes and dconv1 fetch
// halve (decoder-side only; idx/loss untouched). dconv1: 8 output rows per
// block (6 staged input rows) — halo refetch 2x -> 1.5x.
// ---------------------------------------------------------------------------

#define REC_OFF 131073

typedef unsigned short ushort_t;
typedef __attribute__((ext_vector_type(8))) short bf16x8;
typedef __attribute__((ext_vector_type(4))) float f32x4;
typedef __attribute__((ext_vector_type(4))) unsigned int u32x4;
union FragU { u32x4 u; bf16x8 h; };

__device__ __forceinline__ unsigned pack_hilo(float v) {
  unsigned u = __float_as_uint(v);
  unsigned htop = u & 0xFFFF0000u;
  float rf = v - __uint_as_float(htop);
  return htop | (__float_as_uint(rf) >> 16);
}
__device__ __forceinline__ ushort_t bf16_rne(float v) {
  unsigned u = __float_as_uint(v);
  u += 0x7FFFu + ((u >> 16) & 1u);
  return (ushort_t)(u >> 16);
}
__device__ __forceinline__ float bf16_to_f(ushort_t v) {
  return __uint_as_float(((unsigned)v) << 16);
}

__global__ __launch_bounds__(64) void zero_loss_k(float* __restrict__ out) {
  if (threadIdx.x == 0) out[0] = 0.f;
}

// ---- conv2 A-table: [ks=ci0*4+ky][mt][lane][j] bf16 hi/lo -----------------
__global__ __launch_bounds__(256) void repackA2_k(
    const float* __restrict__ ew2,
    ushort_t* __restrict__ hi, ushort_t* __restrict__ lo) {
  int idx = blockIdx.x * 256 + threadIdx.x;        // 131072 total
  int j = idx & 7, l = (idx >> 3) & 63, mt = (idx >> 9) & 3, ks = idx >> 11;
  int ci = ((ks >> 2) << 3) + ((l >> 4) << 1) + (j >> 2);
  int ky = ks & 3, kx = j & 3, d = (mt << 4) + (l & 15);
  float val = ew2[((d << 7) + ci) * 16 + (ky << 2) + kx];
  unsigned u = __float_as_uint(val);
  float rf = val - __uint_as_float(u & 0xFFFF0000u);
  hi[idx] = (ushort_t)(u >> 16);
  lo[idx] = (ushort_t)(__float_as_uint(rf) >> 16);
}

// ---- dconv2 A-table (proven) ----------------------------------------------
__global__ __launch_bounds__(256) void repackA_k(
    const float* __restrict__ dw2,   // dec_w2 (ci=64, co=128, ky, kx)
    ushort_t* __restrict__ hi, ushort_t* __restrict__ lo) {
  int idx = blockIdx.x * 256 + threadIdx.x;        // 131072 total
  int j = idx & 7, l = (idx >> 3) & 63, mt = (idx >> 9) & 7;
  int s = (idx >> 12) & 7, v = idx >> 15;
  int co = (mt << 4) + (l & 15);
  int ci = (s << 3) + ((l >> 4) << 1) + (j >> 2);
  int tap = j & 3;
  int Yp = v >> 1, pX = v & 1;
  int kyA = 1 - Yp, kyB = kyA + 2;
  int kxA = pX ? 0 : 1, kxB = kxA + 2;
  int ky = (tap & 2) ? kyB : kyA;
  int kx = (tap & 1) ? kxA : kxB;
  float val = dw2[(((ci << 7) + co) << 4) + (ky << 2) + kx];
  unsigned u = __float_as_uint(val);
  float rf = val - __uint_as_float(u & 0xFFFF0000u);
  hi[idx] = (ushort_t)(u >> 16);
  lo[idx] = (ushort_t)(__float_as_uint(rf) >> 16);
}

// ---- VQ codebook A-table: [ks(2)][mt(32)][lane(64)][j(8)] bf16 hi/lo ------
__global__ __launch_bounds__(256) void repackCB_k(
    const float* __restrict__ cb,
    ushort_t* __restrict__ hi, ushort_t* __restrict__ lo) {
  int idx = blockIdx.x * 256 + threadIdx.x;        // 32768 total
  int j = idx & 7, l = (idx >> 3) & 63, mt = (idx >> 9) & 31, ks = idx >> 14;
  int code = (mt << 4) + (l & 15);
  int k = (ks << 5) + ((l >> 4) << 3) + j;
  float val = cb[(code << 6) + k];
  unsigned u = __float_as_uint(val);
  float rf = val - __uint_as_float(u & 0xFFFF0000u);
  hi[idx] = (ushort_t)(u >> 16);
  lo[idx] = (ushort_t)(__float_as_uint(rf) >> 16);
}

// ---- csq in C/D fragment order: csqF[(mt*64+l)*4+r] = |cb[code]|^2 --------
__global__ __launch_bounds__(256) void csqF_k(
    const float* __restrict__ cb, float* __restrict__ csqF) {
  int idx = blockIdx.x * 256 + threadIdx.x;        // 8192 total
  int r = idx & 3, l = (idx >> 2) & 63, mt = idx >> 8;
  int code = (mt << 4) + ((l >> 4) << 2) + r;
  const float* cp = cb + (code << 6);
  float s = 0.f;
#pragma unroll
  for (int d = 0; d < 64; ++d) s = fmaf(cp[d], cp[d], s);
  csqF[idx] = s;
}

// ---------------- conv1 (1->128, 4x4, s2, p1) + relu -> packed u32 ----------
__global__ __launch_bounds__(128) void conv1_k(
    const float* __restrict__ x, const float* __restrict__ w1,
    const float* __restrict__ b1, unsigned* __restrict__ hp) {
  int oy = blockIdx.x, b = blockIdx.y, ox = threadIdx.x;
  float xv[16];
#pragma unroll
  for (int ky = 0; ky < 4; ++ky) {
    int iy = 2 * oy - 1 + ky;
#pragma unroll
    for (int kx = 0; kx < 4; ++kx) {
      int ix = 2 * ox - 1 + kx;
      float v = 0.f;
      if (iy >= 0 && iy < 256 && ix >= 0 && ix < 256)
        v = x[(b * 256 + iy) * 256 + ix];
      xv[ky * 4 + kx] = v;
    }
  }
  for (int c = 0; c < 128; ++c) {
    const float* wp = w1 + c * 16;                 // wave-uniform -> s_load
    float acc = b1[c];
#pragma unroll
    for (int k = 0; k < 16; ++k) acc = fmaf(xv[k], wp[k], acc);
    hp[((b * 128 + c) * 128 + oy) * 128 + ox] = pack_hilo(fmaxf(acc, 0.f));
  }
}

// ---------------- conv2 (128->64, 4x4, s2, p1) + relu: bf16x3 MFMA ----------
// 2 y-rows/block, 8 waves (Yloc,mtg,ntg), LDS double-buffered (round 17).
#define C2RL 133
__global__ __launch_bounds__(512) void conv2_k(
    const unsigned* __restrict__ hp, const ushort_t* __restrict__ wCh,
    const ushort_t* __restrict__ wCl, const float* __restrict__ b2,
    float* __restrict__ z) {
  __shared__ unsigned hs[2][8][6][C2RL];           // 51,072 B
  int a = blockIdx.x, b = blockIdx.y;              // outputs y = 2a, 2a+1
  int t = threadIdx.x, l = t & 63;
  int w = __builtin_amdgcn_readfirstlane(t >> 6);  // 0..7
  int Yloc = w >> 2, mtg = (w >> 1) & 1, ntg = w & 1;
  int y = 2 * a + Yloc;
  int g = l >> 4;

  if (t < 48) {                                    // x-halo prezero, both bufs
    int ci = t & 7, r = t >> 3;                    // r in 0..5
    hs[0][ci][r][0] = 0u;
    hs[0][ci][r][129] = 0u;
    hs[1][ci][r][0] = 0u;
    hs[1][ci][r][129] = 0u;
  }

  int c4 = t & 31, ci_l = (t >> 5) & 7, r0 = t >> 8;   // r0 in {0,1}
  int yr[3];
  bool rowok[3];
#pragma unroll
  for (int i = 0; i < 3; ++i) {
    yr[i] = 4 * a - 1 + r0 + 2 * i;
    rowok[i] = yr[i] >= 0 && yr[i] < 128;
  }
  const unsigned* hbase = hp + (((long)b * 128) << 14);

  u32x4 pre[3];
#pragma unroll
  for (int i = 0; i < 3; ++i)
    pre[i] = rowok[i]
        ? *reinterpret_cast<const u32x4*>(
              hbase + (((long)ci_l << 14) + (yr[i] << 7)) + (c4 << 2))
        : (u32x4)0u;
#pragma unroll
  for (int i = 0; i < 3; ++i) {                    // write tile 0 -> buf 0
    unsigned* dst = &hs[0][ci_l][r0 + 2 * i][1 + (c4 << 2)];
    dst[0] = pre[i][0]; dst[1] = pre[i][1];
    dst[2] = pre[i][2]; dst[3] = pre[i][3];
  }
  __syncthreads();

  f32x4 acc[2][2];
#pragma unroll
  for (int ml = 0; ml < 2; ++ml)
#pragma unroll
    for (int nl = 0; nl < 2; ++nl) acc[ml][nl] = (f32x4)0.f;

  for (int rnd = 0; rnd < 16; ++rnd) {
    int cur = rnd & 1;
    if (rnd < 15) {                                // issue next-tile loads
      long cb8 = ((long)((rnd + 1) * 8 + ci_l)) << 14;
#pragma unroll
      for (int i = 0; i < 3; ++i)
        pre[i] = rowok[i]
            ? *reinterpret_cast<const u32x4*>(
                  hbase + cb8 + (yr[i] << 7) + (c4 << 2))
            : (u32x4)0u;
    }
#pragma unroll
    for (int ky = 0; ky < 4; ++ky) {
      int ks = (rnd << 2) + ky;
      int row = 2 * Yloc + ky;                     // LDS row 0..5
      FragU ah[2], al_[2];
#pragma unroll
      for (int ml = 0; ml < 2; ++ml) {
        int mt = (mtg << 1) + ml;
        long aoff = (((long)ks * 4 + mt) * 64 + l) * 8;
        ah[ml].u = *reinterpret_cast<const u32x4*>(wCh + aoff);
        al_[ml].u = *reinterpret_cast<const u32x4*>(wCl + aoff);
      }
#pragma unroll
      for (int nl = 0; nl < 2; ++nl) {
        int nt = (ntg << 1) + nl;
        const unsigned* pa = &hs[cur][g * 2][row][(nt << 5) + 2 * (l & 15)];
        const unsigned* pb = &hs[cur][g * 2 + 1][row][(nt << 5) + 2 * (l & 15)];
        unsigned a0 = pa[0], a1 = pa[1], a2 = pa[2], a3 = pa[3];
        unsigned b0 = pb[0], b1 = pb[1], b2_ = pb[2], b3 = pb[3];
        FragU bh, bl;
        bh.u[0] = __builtin_amdgcn_perm(a1, a0, 0x07060302u);
        bl.u[0] = __builtin_amdgcn_perm(a1, a0, 0x05040100u);
        bh.u[1] = __builtin_amdgcn_perm(a3, a2, 0x07060302u);
        bl.u[1] = __builtin_amdgcn_perm(a3, a2, 0x05040100u);
        bh.u[2] = __builtin_amdgcn_perm(b1, b0, 0x07060302u);
        bl.u[2] = __builtin_amdgcn_perm(b1, b0, 0x05040100u);
        bh.u[3] = __builtin_amdgcn_perm(b3, b2_, 0x07060302u);
        bl.u[3] = __builtin_amdgcn_perm(b3, b2_, 0x05040100u);
#pragma unroll
        for (int ml = 0; ml < 2; ++ml) {
          acc[ml][nl] = __builtin_amdgcn_mfma_f32_16x16x32_bf16(
              ah[ml].h, bh.h, acc[ml][nl], 0, 0, 0);
          acc[ml][nl] = __builtin_amdgcn_mfma_f32_16x16x32_bf16(
              ah[ml].h, bl.h, acc[ml][nl], 0, 0, 0);
          acc[ml][nl] = __builtin_amdgcn_mfma_f32_16x16x32_bf16(
              al_[ml].h, bh.h, acc[ml][nl], 0, 0, 0);
        }
      }
    }
    if (rnd < 15) {                                // write next tile -> buf^1
#pragma unroll
      for (int i = 0; i < 3; ++i) {
        unsigned* dst = &hs[cur ^ 1][ci_l][r0 + 2 * i][1 + (c4 << 2)];
        dst[0] = pre[i][0]; dst[1] = pre[i][1];
        dst[2] = pre[i][2]; dst[3] = pre[i][3];
      }
      __syncthreads();                             // next buf visible; cur free
    }
  }
#pragma unroll
  for (int ml = 0; ml < 2; ++ml) {
#pragma unroll
    for (int nl = 0; nl < 2; ++nl) {
#pragma unroll
      for (int r = 0; r < 4; ++r) {
        int d = (((mtg << 1) + ml) << 4) + (g << 2) + r;
        int x = (((ntg << 1) + nl) << 4) + (l & 15);
        float v = fmaxf(acc[ml][nl][r] + b2[d], 0.f);
        z[((b * 64 + d) * 64 + y) * 64 + x] = v;
      }
    }
  }
}

// ---------------- VQ: bf16x3 MFMA distances + fp32 argmin (chunked) ---------
__global__ __launch_bounds__(256) void vq_k(
    const float* z, const float* __restrict__ cb,
    const ushort_t* __restrict__ cbFh, const ushort_t* __restrict__ cbFl,
    const float* __restrict__ csqF, unsigned int* q_pk,
    float* __restrict__ out, int n0) {
  __shared__ unsigned zS[64 * 67];                 // 17.2 KB
  __shared__ int bk_arr[64];
  __shared__ float redl[4];
  int t = threadIdx.x, l = t & 63;
  int w = __builtin_amdgcn_readfirstlane(t >> 6);
  int nbase = blockIdx.x * 64;
  int b = nbase >> 12, y = (nbase >> 6) & 63;
  long zbase = (long)b * 262144 + y * 64;

  float zv[16];
#pragma unroll
  for (int j = 0; j < 16; ++j) {
    zv[j] = z[zbase + (long)((w << 4) + j) * 4096 + l];
    zS[l * 67 + (w << 4) + j] = pack_hilo(zv[j]);
  }
  __syncthreads();

  int pp = (w << 4) + (l & 15);
  FragU bh[2], bl[2];
#pragma unroll
  for (int ks = 0; ks < 2; ++ks) {
    const unsigned* zp = &zS[pp * 67 + (ks << 5) + ((l >> 4) << 3)];
    unsigned u0 = zp[0], u1 = zp[1], u2 = zp[2], u3 = zp[3];
    unsigned u4 = zp[4], u5 = zp[5], u6 = zp[6], u7 = zp[7];
    bh[ks].u[0] = __builtin_amdgcn_perm(u1, u0, 0x07060302u);
    bl[ks].u[0] = __builtin_amdgcn_perm(u1, u0, 0x05040100u);
    bh[ks].u[1] = __builtin_amdgcn_perm(u3, u2, 0x07060302u);
    bl[ks].u[1] = __builtin_amdgcn_perm(u3, u2, 0x05040100u);
    bh[ks].u[2] = __builtin_amdgcn_perm(u5, u4, 0x07060302u);
    bl[ks].u[2] = __builtin_amdgcn_perm(u5, u4, 0x05040100u);
    bh[ks].u[3] = __builtin_amdgcn_perm(u7, u6, 0x07060302u);
    bl[ks].u[3] = __builtin_amdgcn_perm(u7, u6, 0x05040100u);
  }

  int g = l >> 4;
  float bd = 1e30f;
  int bk = 0;
  for (int mc = 0; mc < 4; ++mc) {                 // 128 codes per chunk
    f32x4 acc[8];
#pragma unroll
    for (int m8 = 0; m8 < 8; ++m8) acc[m8] = (f32x4)0.f;
#pragma unroll
    for (int ks = 0; ks < 2; ++ks) {
#pragma unroll
      for (int m8 = 0; m8 < 8; ++m8) {
        long aoff = (((long)(ks * 32 + mc * 8 + m8) * 64) + l) * 8;
        FragU ah, al_;
        ah.u = *reinterpret_cast<const u32x4*>(cbFh + aoff);
        al_.u = *reinterpret_cast<const u32x4*>(cbFl + aoff);
        acc[m8] = __builtin_amdgcn_mfma_f32_16x16x32_bf16(
            ah.h, bh[ks].h, acc[m8], 0, 0, 0);
        acc[m8] = __builtin_amdgcn_mfma_f32_16x16x32_bf16(
            ah.h, bl[ks].h, acc[m8], 0, 0, 0);
        acc[m8] = __builtin_amdgcn_mfma_f32_16x16x32_bf16(
            al_.h, bh[ks].h, acc[m8], 0, 0, 0);
      }
    }
#pragma unroll
    for (int m8 = 0; m8 < 8; ++m8) {
      int mt = mc * 8 + m8;
      f32x4 cq = *reinterpret_cast<const f32x4*>(csqF + ((mt << 6) + l) * 4);
#pragma unroll
      for (int r = 0; r < 4; ++r) {
        float d = fmaf(-2.f, acc[m8][r], cq[r]);
        if (d < bd) { bd = d; bk = (mt << 4) + (g << 2) + r; }
      }
    }
  }
#pragma unroll
  for (int m = 16; m <= 32; m <<= 1) {
    float d2 = __shfl_xor(bd, m);
    int k2 = __shfl_xor(bk, m);
    if (d2 < bd || (d2 == bd && k2 < bk)) { bd = d2; bk = k2; }
  }
  if (l < 16) {
    bk_arr[(w << 4) + l] = bk;
    out[1 + n0 + nbase + (w << 4) + l] = (float)bk;
  }
  __syncthreads();

  int bkp = bk_arr[l];
  const float* cbest = cb + (bkp << 6) + (w << 4);
  float ls = 0.f;
#pragma unroll
  for (int j = 0; j < 16; ++j) {
    float c = cbest[j];
    q_pk[zbase + (long)((w << 4) + j) * 4096 + l] = pack_hilo(c);
    float df = c - zv[j];
    ls = fmaf(df, df, ls);
  }
#pragma unroll
  for (int m = 32; m; m >>= 1) ls += __shfl_xor(ls, m);
  if (l == 0) redl[w] = ls;
  __syncthreads();
  if (t == 0)
    atomicAdd(out, (redl[0] + redl[1] + redl[2] + redl[3]) * (1.25f / 8388608.f));
}

// ---------------- convT2 (64->128, 4x4, s2, p1) + relu: bf16x3 MFMA ---------
// 2 Y-rows per block, 512 thr = 8 waves (round 14); g stored as bf16 (RNE).
__global__ __launch_bounds__(512) void dconv2_k(
    const unsigned int* __restrict__ q_pk, const ushort_t* __restrict__ wAh,
    const ushort_t* __restrict__ wAl, const float* __restrict__ db2,
    ushort_t* __restrict__ gp) {
  __shared__ unsigned int rows[64][3][68];         // 52,224 B
  int a = blockIdx.x, b = blockIdx.y;              // Y0 = 2a
  int t = threadIdx.x, l = t & 63;
  int w = __builtin_amdgcn_readfirstlane(t >> 6);  // 0..7
  int Yloc = w >> 2, pX = w & 1, coh = (w >> 1) & 1;
  int Y = 2 * a + Yloc;
  int v = (Yloc << 1) | pX;                        // = ((Y&1)<<1)|pX
  int rA = Yloc + 1, rB = Yloc;                    // LDS row idx: yA, yB

  if (t < 192) {
    int ci = t & 63, r = t >> 6;
    rows[ci][r][0] = 0u;
    rows[ci][r][65] = 0u;
  }
  long qb = (long)b * 262144;
#pragma unroll
  for (int r = 0; r < 3; ++r) {
    int yr = a - 1 + r;
    bool ok = (yr >= 0) && (yr < 64);
    for (int s = t; s < 1024; s += 512) {          // 2 iters
      int ci = s >> 4, c4 = s & 15;
      u32x4 val = ok ? *reinterpret_cast<const u32x4*>(
                           q_pk + qb + ci * 4096 + yr * 64 + (c4 << 2))
                     : (u32x4)0u;
      unsigned* dst = &rows[ci][r][1 + (c4 << 2)];
      dst[0] = val[0]; dst[1] = val[1]; dst[2] = val[2]; dst[3] = val[3];
    }
  }
  __syncthreads();

  f32x4 acc[4][4];
#pragma unroll
  for (int mt = 0; mt < 4; ++mt)
#pragma unroll
    for (int nt = 0; nt < 4; ++nt) acc[mt][nt] = (f32x4)0.f;

  for (int s8 = 0; s8 < 8; ++s8) {
    FragU ah[4], al[4];
#pragma unroll
    for (int mt = 0; mt < 4; ++mt) {
      long off = ((((long)(v * 8 + s8) * 8 + (coh * 4 + mt)) * 64 + l) * 8);
      ah[mt].u = *reinterpret_cast<const u32x4*>(wAh + off);
      al[mt].u = *reinterpret_cast<const u32x4*>(wAl + off);
    }
#pragma unroll
    for (int nt = 0; nt < 4; ++nt) {
      int p = nt * 16 + (l & 15) + pX;
      int cc0 = (s8 << 3) + ((l >> 4) << 1);
      unsigned u0 = rows[cc0][rA][p], u1 = rows[cc0][rA][p + 1];
      unsigned u2 = rows[cc0][rB][p], u3 = rows[cc0][rB][p + 1];
      unsigned u4 = rows[cc0 + 1][rA][p], u5 = rows[cc0 + 1][rA][p + 1];
      unsigned u6 = rows[cc0 + 1][rB][p], u7 = rows[cc0 + 1][rB][p + 1];
      FragU bh, bl;
      bh.u[0] = (u0 >> 16) | (u1 & 0xFFFF0000u);
      bl.u[0] = (u0 & 0xFFFFu) | (u1 << 16);
      bh.u[1] = (u2 >> 16) | (u3 & 0xFFFF0000u);
      bl.u[1] = (u2 & 0xFFFFu) | (u3 << 16);
      bh.u[2] = (u4 >> 16) | (u5 & 0xFFFF0000u);
      bl.u[2] = (u4 & 0xFFFFu) | (u5 << 16);
      bh.u[3] = (u6 >> 16) | (u7 & 0xFFFF0000u);
      bl.u[3] = (u6 & 0xFFFFu) | (u7 << 16);
#pragma unroll
      for (int mt = 0; mt < 4; ++mt) {
        acc[mt][nt] = __builtin_amdgcn_mfma_f32_16x16x32_bf16(
            ah[mt].h, bh.h, acc[mt][nt], 0, 0, 0);
        acc[mt][nt] = __builtin_amdgcn_mfma_f32_16x16x32_bf16(
            ah[mt].h, bl.h, acc[mt][nt], 0, 0, 0);
        acc[mt][nt] = __builtin_amdgcn_mfma_f32_16x16x32_bf16(
            al[mt].h, bh.h, acc[mt][nt], 0, 0, 0);
      }
    }
  }

#pragma unroll
  for (int mt = 0; mt < 4; ++mt) {
#pragma unroll
    for (int r = 0; r < 4; ++r) {
      int co = ((coh * 4 + mt) << 4) + ((l >> 4) << 2) + r;
      float bias = db2[co];
#pragma unroll
      for (int nt = 0; nt < 4; ++nt) {
        int X = ((nt << 4) + (l & 15)) * 2 + pX;
        float val = fmaxf(acc[mt][nt][r] + bias, 0.f);
        gp[((b * 128 + co) * 128 + Y) * 128 + X] = bf16_rne(val);
      }
    }
  }
}

// ---------------- convT1 (128->1, 4x4, s2, p1) + sigmoid --------------------
// Direct-load bf16 g. 8 output rows/block (6 input rows, refetch 1.5x).
__global__ __launch_bounds__(256) void dconv1_k(
    const ushort_t* __restrict__ g, const float* __restrict__ wd1,
    const float* __restrict__ db1, float* __restrict__ rec) {
  int a3 = blockIdx.x, b = blockIdx.y;
  int t = threadIdx.x;
  int w = __builtin_amdgcn_readfirstlane(t >> 6);
  int l = t & 63;
  int xh = w >> 1, pX = w & 1;
  int L = xh * 64 + l;                       // X = 2L + pX
  int kxA = pX ? 0 : 1, kxB = kxA + 2;
  int ixH = L + pX, ixL = L + pX - 1;
  bool okH = ixH < 128, okL = ixL >= 0;
  int yy0 = 4 * a3 - 1;
  bool vy[6];
#pragma unroll
  for (int r = 0; r < 6; ++r) vy[r] = (yy0 + r) >= 0 && (yy0 + r) < 128;

  const ushort_t* gb = g + ((long)b * 128) * 16384 + (long)yy0 * 128;
  float acc[8] = {0.f, 0.f, 0.f, 0.f, 0.f, 0.f, 0.f, 0.f};

  for (int ci = 0; ci < 128; ci += 2) {
    const ushort_t* p0 = gb + (long)ci * 16384;
    const ushort_t* p1 = p0 + 16384;
    float hi0[6], lo0[6], hi1[6], lo1[6];
#pragma unroll
    for (int r = 0; r < 6; ++r) {
      const ushort_t* q0 = p0 + r * 128;
      const ushort_t* q1 = p1 + r * 128;
      hi0[r] = (vy[r] && okH) ? bf16_to_f(q0[ixH]) : 0.f;
      lo0[r] = (vy[r] && okL) ? bf16_to_f(q0[ixL]) : 0.f;
      hi1[r] = (vy[r] && okH) ? bf16_to_f(q1[ixH]) : 0.f;
      lo1[r] = (vy[r] && okL) ? bf16_to_f(q1[ixL]) : 0.f;
    }
    const float* wp0 = wd1 + ci * 16;        // wave-uniform -> s_load
    const float* wp1 = wp0 + 16;
#pragma unroll
    for (int j = 0; j < 8; ++j) {
      int kyA = (j + 1) & 1, kyB = kyA + 2;
      int rA = ((j + 1) >> 1) + 1;           // in [1,5]
      float v = acc[j];
      v = fmaf(wp0[kyA * 4 + kxA], hi0[rA], v);
      v = fmaf(wp0[kyA * 4 + kxB], lo0[rA], v);
      v = fmaf(wp0[kyB * 4 + kxA], hi0[rA - 1], v);
      v = fmaf(wp0[kyB * 4 + kxB], lo0[rA - 1], v);
      v = fmaf(wp1[kyA * 4 + kxA], hi1[rA], v);
      v = fmaf(wp1[kyA * 4 + kxB], lo1[rA], v);
      v = fmaf(wp1[kyB * 4 + kxA], hi1[rA - 1], v);
      v = fmaf(wp1[kyB * 4 + kxB], lo1[rA - 1], v);
      acc[j] = v;
    }
  }
  float bb = db1[0];
#pragma unroll
  for (int j = 0; j < 8; ++j) {
    float v = acc[j] + bb;
    v = 1.f / (1.f + __expf(-v));
    rec[((b * 256 + 8 * a3 + j) * 256) + 2 * L + pX] = v;
  }
}

// ---------------------------------------------------------------------------
extern "C" void kernel_launch(void* const* d_in, const int* in_sizes, int n_in,
                              void* d_out, int out_size, void* d_ws, size_t ws_size,
                              hipStream_t stream) {
  const float* x      = (const float*)d_in[0];
  const float* enc_w1 = (const float*)d_in[1];
  const float* enc_b1 = (const float*)d_in[2];
  const float* enc_w2 = (const float*)d_in[3];
  const float* enc_b2 = (const float*)d_in[4];
  const float* cb     = (const float*)d_in[5];
  const float* dec_w2 = (const float*)d_in[6];
  const float* dec_b2 = (const float*)d_in[7];
  const float* dec_w1 = (const float*)d_in[8];
  const float* dec_b1 = (const float*)d_in[9];

  float* out = (float*)d_out;
  float* ws  = (float*)d_ws;
  ushort_t* wCh  = (ushort_t*)ws;                   // 131072 ushort = 65536 f
  ushort_t* wCl  = (ushort_t*)(ws + 65536);
  ushort_t* wAh  = (ushort_t*)(ws + 131072);
  ushort_t* wAl  = (ushort_t*)(ws + 196608);
  ushort_t* cbFh = (ushort_t*)(ws + 262144);        // 32768 ushort = 16384 f
  ushort_t* cbFl = (ushort_t*)(ws + 278528);
  float* csqF = ws + 294912;                        // 8192 f
  float* dyn  = ws + 303104;                        // chunk buffers

  // Per-image: h_pk = 2,097,152 u32 (g bf16 aliases), z/q_pk = 262,144.
  const size_t PER_IMG = 2097152 + 262144;                   // 2,359,296 elems
  size_t avail = (ws_size / 4 > 303104 + 64) ? ws_size / 4 - 303104 - 64 : 0;
  int CB = 32;
  while (CB > 1 && (size_t)CB * PER_IMG > avail) CB >>= 1;

  zero_loss_k<<<dim3(1), 64, 0, stream>>>(out);
  repackA2_k<<<dim3(512), 256, 0, stream>>>(enc_w2, wCh, wCl);
  repackA_k<<<dim3(512), 256, 0, stream>>>(dec_w2, wAh, wAl);
  repackCB_k<<<dim3(128), 256, 0, stream>>>(cb, cbFh, cbFl);
  csqF_k<<<dim3(32), 256, 0, stream>>>(cb, csqF);

  for (int b0 = 0; b0 < 32; b0 += CB) {
    unsigned* hp = (unsigned*)dyn;                    // CB*2097152 (g aliases)
    float* zq = dyn + (size_t)CB * 2097152;           // CB*262144 (q_pk aliases)
    conv1_k<<<dim3(128, CB), 128, 0, stream>>>(
        x + (size_t)b0 * 65536, enc_w1, enc_b1, hp);
    conv2_k<<<dim3(32, CB), 512, 0, stream>>>(hp, wCh, wCl, enc_b2, zq);
    vq_k<<<dim3(CB * 64), 256, 0, stream>>>(
        zq, cb, cbFh, cbFl, csqF, (unsigned int*)zq, out, b0 * 4096);
    dconv2_k<<<dim3(64, CB), 512, 0, stream>>>(
        (const unsigned int*)zq, wAh, wAl, dec_b2, (ushort_t*)dyn /*g bf16*/);
    dconv1_k<<<dim3(32, CB), 256, 0, stream>>>(
        (const ushort_t*)dyn /*g*/, dec_w1, dec_b1,
        out + REC_OFF + (size_t)b0 * 65536);
  }
}

// Round 19
// 506.164 us; speedup vs baseline: 1.9747x; 1.9747x over previous
//
#include <hip/hip_runtime.h>
#include <math.h>

// ---------------------------------------------------------------------------
// VQ-VAE forward, bf16x3-MFMA for conv2, convT2 AND VQ distances.
//  x (32,1,256,256) -> h_pk (u32 hi|lo) -> z (f32) -> VQ -> q_pk (u32 hi|lo)
//  -> g (bf16 ushort, aliases h_pk) -> x_recon (32,1,256,256)
// d_out: [0]=vq_loss, [1..131072]=idx (as float), [131073..]=x_recon
// Fragment conventions (HW-verified, absmax 0.0 rounds 4-17):
//   A/B: lane l holds k_local = 8*(l>>4)+j, m/n = l&15
//   C/D: row = (l>>4)*4 + reg, col = l&15
// Round 19: dconv1 rebuilt for bf16 g — lane owns X=4l..4l+3; inputs are one
// aligned u32 word (cols 2l,2l+1) + neighbor halves via shfl_up/down; stores
// are f32x4. (Round-18's 2B scalar loads killed MLP: 306us, 175 GB/s.)
// ---------------------------------------------------------------------------

#define REC_OFF 131073

typedef unsigned short ushort_t;
typedef __attribute__((ext_vector_type(8))) short bf16x8;
typedef __attribute__((ext_vector_type(4))) float f32x4;
typedef __attribute__((ext_vector_type(4))) unsigned int u32x4;
union FragU { u32x4 u; bf16x8 h; };

__device__ __forceinline__ unsigned pack_hilo(float v) {
  unsigned u = __float_as_uint(v);
  unsigned htop = u & 0xFFFF0000u;
  float rf = v - __uint_as_float(htop);
  return htop | (__float_as_uint(rf) >> 16);
}
__device__ __forceinline__ ushort_t bf16_rne(float v) {
  unsigned u = __float_as_uint(v);
  u += 0x7FFFu + ((u >> 16) & 1u);
  return (ushort_t)(u >> 16);
}

__global__ __launch_bounds__(64) void zero_loss_k(float* __restrict__ out) {
  if (threadIdx.x == 0) out[0] = 0.f;
}

// ---- conv2 A-table: [ks=ci0*4+ky][mt][lane][j] bf16 hi/lo -----------------
__global__ __launch_bounds__(256) void repackA2_k(
    const float* __restrict__ ew2,
    ushort_t* __restrict__ hi, ushort_t* __restrict__ lo) {
  int idx = blockIdx.x * 256 + threadIdx.x;        // 131072 total
  int j = idx & 7, l = (idx >> 3) & 63, mt = (idx >> 9) & 3, ks = idx >> 11;
  int ci = ((ks >> 2) << 3) + ((l >> 4) << 1) + (j >> 2);
  int ky = ks & 3, kx = j & 3, d = (mt << 4) + (l & 15);
  float val = ew2[((d << 7) + ci) * 16 + (ky << 2) + kx];
  unsigned u = __float_as_uint(val);
  float rf = val - __uint_as_float(u & 0xFFFF0000u);
  hi[idx] = (ushort_t)(u >> 16);
  lo[idx] = (ushort_t)(__float_as_uint(rf) >> 16);
}

// ---- dconv2 A-table (proven) ----------------------------------------------
__global__ __launch_bounds__(256) void repackA_k(
    const float* __restrict__ dw2,   // dec_w2 (ci=64, co=128, ky, kx)
    ushort_t* __restrict__ hi, ushort_t* __restrict__ lo) {
  int idx = blockIdx.x * 256 + threadIdx.x;        // 131072 total
  int j = idx & 7, l = (idx >> 3) & 63, mt = (idx >> 9) & 7;
  int s = (idx >> 12) & 7, v = idx >> 15;
  int co = (mt << 4) + (l & 15);
  int ci = (s << 3) + ((l >> 4) << 1) + (j >> 2);
  int tap = j & 3;
  int Yp = v >> 1, pX = v & 1;
  int kyA = 1 - Yp, kyB = kyA + 2;
  int kxA = pX ? 0 : 1, kxB = kxA + 2;
  int ky = (tap & 2) ? kyB : kyA;
  int kx = (tap & 1) ? kxA : kxB;
  float val = dw2[(((ci << 7) + co) << 4) + (ky << 2) + kx];
  unsigned u = __float_as_uint(val);
  float rf = val - __uint_as_float(u & 0xFFFF0000u);
  hi[idx] = (ushort_t)(u >> 16);
  lo[idx] = (ushort_t)(__float_as_uint(rf) >> 16);
}

// ---- VQ codebook A-table: [ks(2)][mt(32)][lane(64)][j(8)] bf16 hi/lo ------
__global__ __launch_bounds__(256) void repackCB_k(
    const float* __restrict__ cb,
    ushort_t* __restrict__ hi, ushort_t* __restrict__ lo) {
  int idx = blockIdx.x * 256 + threadIdx.x;        // 32768 total
  int j = idx & 7, l = (idx >> 3) & 63, mt = (idx >> 9) & 31, ks = idx >> 14;
  int code = (mt << 4) + (l & 15);
  int k = (ks << 5) + ((l >> 4) << 3) + j;
  float val = cb[(code << 6) + k];
  unsigned u = __float_as_uint(val);
  float rf = val - __uint_as_float(u & 0xFFFF0000u);
  hi[idx] = (ushort_t)(u >> 16);
  lo[idx] = (ushort_t)(__float_as_uint(rf) >> 16);
}

// ---- csq in C/D fragment order: csqF[(mt*64+l)*4+r] = |cb[code]|^2 --------
__global__ __launch_bounds__(256) void csqF_k(
    const float* __restrict__ cb, float* __restrict__ csqF) {
  int idx = blockIdx.x * 256 + threadIdx.x;        // 8192 total
  int r = idx & 3, l = (idx >> 2) & 63, mt = idx >> 8;
  int code = (mt << 4) + ((l >> 4) << 2) + r;
  const float* cp = cb + (code << 6);
  float s = 0.f;
#pragma unroll
  for (int d = 0; d < 64; ++d) s = fmaf(cp[d], cp[d], s);
  csqF[idx] = s;
}

// ---------------- conv1 (1->128, 4x4, s2, p1) + relu -> packed u32 ----------
__global__ __launch_bounds__(128) void conv1_k(
    const float* __restrict__ x, const float* __restrict__ w1,
    const float* __restrict__ b1, unsigned* __restrict__ hp) {
  int oy = blockIdx.x, b = blockIdx.y, ox = threadIdx.x;
  float xv[16];
#pragma unroll
  for (int ky = 0; ky < 4; ++ky) {
    int iy = 2 * oy - 1 + ky;
#pragma unroll
    for (int kx = 0; kx < 4; ++kx) {
      int ix = 2 * ox - 1 + kx;
      float v = 0.f;
      if (iy >= 0 && iy < 256 && ix >= 0 && ix < 256)
        v = x[(b * 256 + iy) * 256 + ix];
      xv[ky * 4 + kx] = v;
    }
  }
  for (int c = 0; c < 128; ++c) {
    const float* wp = w1 + c * 16;                 // wave-uniform -> s_load
    float acc = b1[c];
#pragma unroll
    for (int k = 0; k < 16; ++k) acc = fmaf(xv[k], wp[k], acc);
    hp[((b * 128 + c) * 128 + oy) * 128 + ox] = pack_hilo(fmaxf(acc, 0.f));
  }
}

// ---------------- conv2 (128->64, 4x4, s2, p1) + relu: bf16x3 MFMA ----------
// 2 y-rows/block, 8 waves (Yloc,mtg,ntg), LDS double-buffered (round 17).
#define C2RL 133
__global__ __launch_bounds__(512) void conv2_k(
    const unsigned* __restrict__ hp, const ushort_t* __restrict__ wCh,
    const ushort_t* __restrict__ wCl, const float* __restrict__ b2,
    float* __restrict__ z) {
  __shared__ unsigned hs[2][8][6][C2RL];           // 51,072 B
  int a = blockIdx.x, b = blockIdx.y;              // outputs y = 2a, 2a+1
  int t = threadIdx.x, l = t & 63;
  int w = __builtin_amdgcn_readfirstlane(t >> 6);  // 0..7
  int Yloc = w >> 2, mtg = (w >> 1) & 1, ntg = w & 1;
  int y = 2 * a + Yloc;
  int g = l >> 4;

  if (t < 48) {                                    // x-halo prezero, both bufs
    int ci = t & 7, r = t >> 3;                    // r in 0..5
    hs[0][ci][r][0] = 0u;
    hs[0][ci][r][129] = 0u;
    hs[1][ci][r][0] = 0u;
    hs[1][ci][r][129] = 0u;
  }

  int c4 = t & 31, ci_l = (t >> 5) & 7, r0 = t >> 8;   // r0 in {0,1}
  int yr[3];
  bool rowok[3];
#pragma unroll
  for (int i = 0; i < 3; ++i) {
    yr[i] = 4 * a - 1 + r0 + 2 * i;
    rowok[i] = yr[i] >= 0 && yr[i] < 128;
  }
  const unsigned* hbase = hp + (((long)b * 128) << 14);

  u32x4 pre[3];
#pragma unroll
  for (int i = 0; i < 3; ++i)
    pre[i] = rowok[i]
        ? *reinterpret_cast<const u32x4*>(
              hbase + (((long)ci_l << 14) + (yr[i] << 7)) + (c4 << 2))
        : (u32x4)0u;
#pragma unroll
  for (int i = 0; i < 3; ++i) {                    // write tile 0 -> buf 0
    unsigned* dst = &hs[0][ci_l][r0 + 2 * i][1 + (c4 << 2)];
    dst[0] = pre[i][0]; dst[1] = pre[i][1];
    dst[2] = pre[i][2]; dst[3] = pre[i][3];
  }
  __syncthreads();

  f32x4 acc[2][2];
#pragma unroll
  for (int ml = 0; ml < 2; ++ml)
#pragma unroll
    for (int nl = 0; nl < 2; ++nl) acc[ml][nl] = (f32x4)0.f;

  for (int rnd = 0; rnd < 16; ++rnd) {
    int cur = rnd & 1;
    if (rnd < 15) {                                // issue next-tile loads
      long cb8 = ((long)((rnd + 1) * 8 + ci_l)) << 14;
#pragma unroll
      for (int i = 0; i < 3; ++i)
        pre[i] = rowok[i]
            ? *reinterpret_cast<const u32x4*>(
                  hbase + cb8 + (yr[i] << 7) + (c4 << 2))
            : (u32x4)0u;
    }
#pragma unroll
    for (int ky = 0; ky < 4; ++ky) {
      int ks = (rnd << 2) + ky;
      int row = 2 * Yloc + ky;                     // LDS row 0..5
      FragU ah[2], al_[2];
#pragma unroll
      for (int ml = 0; ml < 2; ++ml) {
        int mt = (mtg << 1) + ml;
        long aoff = (((long)ks * 4 + mt) * 64 + l) * 8;
        ah[ml].u = *reinterpret_cast<const u32x4*>(wCh + aoff);
        al_[ml].u = *reinterpret_cast<const u32x4*>(wCl + aoff);
      }
#pragma unroll
      for (int nl = 0; nl < 2; ++nl) {
        int nt = (ntg << 1) + nl;
        const unsigned* pa = &hs[cur][g * 2][row][(nt << 5) + 2 * (l & 15)];
        const unsigned* pb = &hs[cur][g * 2 + 1][row][(nt << 5) + 2 * (l & 15)];
        unsigned a0 = pa[0], a1 = pa[1], a2 = pa[2], a3 = pa[3];
        unsigned b0 = pb[0], b1 = pb[1], b2_ = pb[2], b3 = pb[3];
        FragU bh, bl;
        bh.u[0] = __builtin_amdgcn_perm(a1, a0, 0x07060302u);
        bl.u[0] = __builtin_amdgcn_perm(a1, a0, 0x05040100u);
        bh.u[1] = __builtin_amdgcn_perm(a3, a2, 0x07060302u);
        bl.u[1] = __builtin_amdgcn_perm(a3, a2, 0x05040100u);
        bh.u[2] = __builtin_amdgcn_perm(b1, b0, 0x07060302u);
        bl.u[2] = __builtin_amdgcn_perm(b1, b0, 0x05040100u);
        bh.u[3] = __builtin_amdgcn_perm(b3, b2_, 0x07060302u);
        bl.u[3] = __builtin_amdgcn_perm(b3, b2_, 0x05040100u);
#pragma unroll
        for (int ml = 0; ml < 2; ++ml) {
          acc[ml][nl] = __builtin_amdgcn_mfma_f32_16x16x32_bf16(
              ah[ml].h, bh.h, acc[ml][nl], 0, 0, 0);
          acc[ml][nl] = __builtin_amdgcn_mfma_f32_16x16x32_bf16(
              ah[ml].h, bl.h, acc[ml][nl], 0, 0, 0);
          acc[ml][nl] = __builtin_amdgcn_mfma_f32_16x16x32_bf16(
              al_[ml].h, bh.h, acc[ml][nl], 0, 0, 0);
        }
      }
    }
    if (rnd < 15) {                                // write next tile -> buf^1
#pragma unroll
      for (int i = 0; i < 3; ++i) {
        unsigned* dst = &hs[cur ^ 1][ci_l][r0 + 2 * i][1 + (c4 << 2)];
        dst[0] = pre[i][0]; dst[1] = pre[i][1];
        dst[2] = pre[i][2]; dst[3] = pre[i][3];
      }
      __syncthreads();                             // next buf visible; cur free
    }
  }
#pragma unroll
  for (int ml = 0; ml < 2; ++ml) {
#pragma unroll
    for (int nl = 0; nl < 2; ++nl) {
#pragma unroll
      for (int r = 0; r < 4; ++r) {
        int d = (((mtg << 1) + ml) << 4) + (g << 2) + r;
        int x = (((ntg << 1) + nl) << 4) + (l & 15);
        float v = fmaxf(acc[ml][nl][r] + b2[d], 0.f);
        z[((b * 64 + d) * 64 + y) * 64 + x] = v;
      }
    }
  }
}

// ---------------- VQ: bf16x3 MFMA distances + fp32 argmin (chunked) ---------
__global__ __launch_bounds__(256) void vq_k(
    const float* z, const float* __restrict__ cb,
    const ushort_t* __restrict__ cbFh, const ushort_t* __restrict__ cbFl,
    const float* __restrict__ csqF, unsigned int* q_pk,
    float* __restrict__ out, int n0) {
  __shared__ unsigned zS[64 * 67];                 // 17.2 KB
  __shared__ int bk_arr[64];
  __shared__ float redl[4];
  int t = threadIdx.x, l = t & 63;
  int w = __builtin_amdgcn_readfirstlane(t >> 6);
  int nbase = blockIdx.x * 64;
  int b = nbase >> 12, y = (nbase >> 6) & 63;
  long zbase = (long)b * 262144 + y * 64;

  float zv[16];
#pragma unroll
  for (int j = 0; j < 16; ++j) {
    zv[j] = z[zbase + (long)((w << 4) + j) * 4096 + l];
    zS[l * 67 + (w << 4) + j] = pack_hilo(zv[j]);
  }
  __syncthreads();

  int pp = (w << 4) + (l & 15);
  FragU bh[2], bl[2];
#pragma unroll
  for (int ks = 0; ks < 2; ++ks) {
    const unsigned* zp = &zS[pp * 67 + (ks << 5) + ((l >> 4) << 3)];
    unsigned u0 = zp[0], u1 = zp[1], u2 = zp[2], u3 = zp[3];
    unsigned u4 = zp[4], u5 = zp[5], u6 = zp[6], u7 = zp[7];
    bh[ks].u[0] = __builtin_amdgcn_perm(u1, u0, 0x07060302u);
    bl[ks].u[0] = __builtin_amdgcn_perm(u1, u0, 0x05040100u);
    bh[ks].u[1] = __builtin_amdgcn_perm(u3, u2, 0x07060302u);
    bl[ks].u[1] = __builtin_amdgcn_perm(u3, u2, 0x05040100u);
    bh[ks].u[2] = __builtin_amdgcn_perm(u5, u4, 0x07060302u);
    bl[ks].u[2] = __builtin_amdgcn_perm(u5, u4, 0x05040100u);
    bh[ks].u[3] = __builtin_amdgcn_perm(u7, u6, 0x07060302u);
    bl[ks].u[3] = __builtin_amdgcn_perm(u7, u6, 0x05040100u);
  }

  int g = l >> 4;
  float bd = 1e30f;
  int bk = 0;
  for (int mc = 0; mc < 4; ++mc) {                 // 128 codes per chunk
    f32x4 acc[8];
#pragma unroll
    for (int m8 = 0; m8 < 8; ++m8) acc[m8] = (f32x4)0.f;
#pragma unroll
    for (int ks = 0; ks < 2; ++ks) {
#pragma unroll
      for (int m8 = 0; m8 < 8; ++m8) {
        long aoff = (((long)(ks * 32 + mc * 8 + m8) * 64) + l) * 8;
        FragU ah, al_;
        ah.u = *reinterpret_cast<const u32x4*>(cbFh + aoff);
        al_.u = *reinterpret_cast<const u32x4*>(cbFl + aoff);
        acc[m8] = __builtin_amdgcn_mfma_f32_16x16x32_bf16(
            ah.h, bh[ks].h, acc[m8], 0, 0, 0);
        acc[m8] = __builtin_amdgcn_mfma_f32_16x16x32_bf16(
            ah.h, bl[ks].h, acc[m8], 0, 0, 0);
        acc[m8] = __builtin_amdgcn_mfma_f32_16x16x32_bf16(
            al_.h, bh[ks].h, acc[m8], 0, 0, 0);
      }
    }
#pragma unroll
    for (int m8 = 0; m8 < 8; ++m8) {
      int mt = mc * 8 + m8;
      f32x4 cq = *reinterpret_cast<const f32x4*>(csqF + ((mt << 6) + l) * 4);
#pragma unroll
      for (int r = 0; r < 4; ++r) {
        float d = fmaf(-2.f, acc[m8][r], cq[r]);
        if (d < bd) { bd = d; bk = (mt << 4) + (g << 2) + r; }
      }
    }
  }
#pragma unroll
  for (int m = 16; m <= 32; m <<= 1) {
    float d2 = __shfl_xor(bd, m);
    int k2 = __shfl_xor(bk, m);
    if (d2 < bd || (d2 == bd && k2 < bk)) { bd = d2; bk = k2; }
  }
  if (l < 16) {
    bk_arr[(w << 4) + l] = bk;
    out[1 + n0 + nbase + (w << 4) + l] = (float)bk;
  }
  __syncthreads();

  int bkp = bk_arr[l];
  const float* cbest = cb + (bkp << 6) + (w << 4);
  float ls = 0.f;
#pragma unroll
  for (int j = 0; j < 16; ++j) {
    float c = cbest[j];
    q_pk[zbase + (long)((w << 4) + j) * 4096 + l] = pack_hilo(c);
    float df = c - zv[j];
    ls = fmaf(df, df, ls);
  }
#pragma unroll
  for (int m = 32; m; m >>= 1) ls += __shfl_xor(ls, m);
  if (l == 0) redl[w] = ls;
  __syncthreads();
  if (t == 0)
    atomicAdd(out, (redl[0] + redl[1] + redl[2] + redl[3]) * (1.25f / 8388608.f));
}

// ---------------- convT2 (64->128, 4x4, s2, p1) + relu: bf16x3 MFMA ---------
// 2 Y-rows per block, 512 thr = 8 waves (round 14); g stored as bf16 (RNE).
__global__ __launch_bounds__(512) void dconv2_k(
    const unsigned int* __restrict__ q_pk, const ushort_t* __restrict__ wAh,
    const ushort_t* __restrict__ wAl, const float* __restrict__ db2,
    ushort_t* __restrict__ gp) {
  __shared__ unsigned int rows[64][3][68];         // 52,224 B
  int a = blockIdx.x, b = blockIdx.y;              // Y0 = 2a
  int t = threadIdx.x, l = t & 63;
  int w = __builtin_amdgcn_readfirstlane(t >> 6);  // 0..7
  int Yloc = w >> 2, pX = w & 1, coh = (w >> 1) & 1;
  int Y = 2 * a + Yloc;
  int v = (Yloc << 1) | pX;                        // = ((Y&1)<<1)|pX
  int rA = Yloc + 1, rB = Yloc;                    // LDS row idx: yA, yB

  if (t < 192) {
    int ci = t & 63, r = t >> 6;
    rows[ci][r][0] = 0u;
    rows[ci][r][65] = 0u;
  }
  long qb = (long)b * 262144;
#pragma unroll
  for (int r = 0; r < 3; ++r) {
    int yr = a - 1 + r;
    bool ok = (yr >= 0) && (yr < 64);
    for (int s = t; s < 1024; s += 512) {          // 2 iters
      int ci = s >> 4, c4 = s & 15;
      u32x4 val = ok ? *reinterpret_cast<const u32x4*>(
                           q_pk + qb + ci * 4096 + yr * 64 + (c4 << 2))
                     : (u32x4)0u;
      unsigned* dst = &rows[ci][r][1 + (c4 << 2)];
      dst[0] = val[0]; dst[1] = val[1]; dst[2] = val[2]; dst[3] = val[3];
    }
  }
  __syncthreads();

  f32x4 acc[4][4];
#pragma unroll
  for (int mt = 0; mt < 4; ++mt)
#pragma unroll
    for (int nt = 0; nt < 4; ++nt) acc[mt][nt] = (f32x4)0.f;

  for (int s8 = 0; s8 < 8; ++s8) {
    FragU ah[4], al[4];
#pragma unroll
    for (int mt = 0; mt < 4; ++mt) {
      long off = ((((long)(v * 8 + s8) * 8 + (coh * 4 + mt)) * 64 + l) * 8);
      ah[mt].u = *reinterpret_cast<const u32x4*>(wAh + off);
      al[mt].u = *reinterpret_cast<const u32x4*>(wAl + off);
    }
#pragma unroll
    for (int nt = 0; nt < 4; ++nt) {
      int p = nt * 16 + (l & 15) + pX;
      int cc0 = (s8 << 3) + ((l >> 4) << 1);
      unsigned u0 = rows[cc0][rA][p], u1 = rows[cc0][rA][p + 1];
      unsigned u2 = rows[cc0][rB][p], u3 = rows[cc0][rB][p + 1];
      unsigned u4 = rows[cc0 + 1][rA][p], u5 = rows[cc0 + 1][rA][p + 1];
      unsigned u6 = rows[cc0 + 1][rB][p], u7 = rows[cc0 + 1][rB][p + 1];
      FragU bh, bl;
      bh.u[0] = (u0 >> 16) | (u1 & 0xFFFF0000u);
      bl.u[0] = (u0 & 0xFFFFu) | (u1 << 16);
      bh.u[1] = (u2 >> 16) | (u3 & 0xFFFF0000u);
      bl.u[1] = (u2 & 0xFFFFu) | (u3 << 16);
      bh.u[2] = (u4 >> 16) | (u5 & 0xFFFF0000u);
      bl.u[2] = (u4 & 0xFFFFu) | (u5 << 16);
      bh.u[3] = (u6 >> 16) | (u7 & 0xFFFF0000u);
      bl.u[3] = (u6 & 0xFFFFu) | (u7 << 16);
#pragma unroll
      for (int mt = 0; mt < 4; ++mt) {
        acc[mt][nt] = __builtin_amdgcn_mfma_f32_16x16x32_bf16(
            ah[mt].h, bh.h, acc[mt][nt], 0, 0, 0);
        acc[mt][nt] = __builtin_amdgcn_mfma_f32_16x16x32_bf16(
            ah[mt].h, bl.h, acc[mt][nt], 0, 0, 0);
        acc[mt][nt] = __builtin_amdgcn_mfma_f32_16x16x32_bf16(
            al[mt].h, bh.h, acc[mt][nt], 0, 0, 0);
      }
    }
  }

#pragma unroll
  for (int mt = 0; mt < 4; ++mt) {
#pragma unroll
    for (int r = 0; r < 4; ++r) {
      int co = ((coh * 4 + mt) << 4) + ((l >> 4) << 2) + r;
      float bias = db2[co];
#pragma unroll
      for (int nt = 0; nt < 4; ++nt) {
        int X = ((nt << 4) + (l & 15)) * 2 + pX;
        float val = fmaxf(acc[mt][nt][r] + bias, 0.f);
        gp[((b * 128 + co) * 128 + Y) * 128 + X] = bf16_rne(val);
      }
    }
  }
}

// ---------------- convT1 (128->1, 4x4, s2, p1) + sigmoid --------------------
// bf16 g via u32 word loads + shfl neighbors. Block = 4 waves; wave w: output
// rows Y0=8a+2w, Y0+1; lane l: output cols X=4l..4l+3 (input word l = cols
// 2l,2l+1; col 2l-1 from shfl_up, col 2l+2 from shfl_down). f32x4 stores.
__global__ __launch_bounds__(256) void dconv1_k(
    const ushort_t* __restrict__ g, const float* __restrict__ wd1,
    const float* __restrict__ db1, float* __restrict__ rec) {
  int a = blockIdx.x, b = blockIdx.y;
  int t = threadIdx.x, l = t & 63;
  int w = __builtin_amdgcn_readfirstlane(t >> 6);
  int q = 4 * a + w;                         // input row center; rows q-1,q,q+1
  int Y0 = 8 * a + 2 * w;
  bool ok0 = q >= 1;                         // row q-1 valid
  bool ok2 = q <= 126;                       // row q+1 valid
  const unsigned* gw = (const unsigned*)g;
  long cbase = (long)b * 128;

  float acc[8] = {0.f, 0.f, 0.f, 0.f, 0.f, 0.f, 0.f, 0.f};

  for (int ci = 0; ci < 128; ci += 2) {
    long i0 = (cbase + ci) * 128;            // row-index base (x128 rows)
    long i1 = i0 + 128;
    unsigned wa[3], wb[3];
    wa[0] = ok0 ? gw[(i0 + q - 1) * 64 + l] : 0u;
    wa[1] = gw[(i0 + q) * 64 + l];
    wa[2] = ok2 ? gw[(i0 + q + 1) * 64 + l] : 0u;
    wb[0] = ok0 ? gw[(i1 + q - 1) * 64 + l] : 0u;
    wb[1] = gw[(i1 + q) * 64 + l];
    wb[2] = ok2 ? gw[(i1 + q + 1) * 64 + l] : 0u;

    const float* wp0 = wd1 + ci * 16;        // wave-uniform -> s_load
    const float* wp1 = wp0 + 16;
#pragma unroll
    for (int h = 0; h < 2; ++h) {
      const unsigned* wrd = h ? wb : wa;
      const float* wp = h ? wp1 : wp0;
      float cm1[3], c0[3], c1[3], c2[3];
#pragma unroll
      for (int r = 0; r < 3; ++r) {
        unsigned wd = wrd[r];
        unsigned up = __shfl_up(wd, 1);      // lane l-1's word
        unsigned dn = __shfl_down(wd, 1);    // lane l+1's word
        if (l == 0) up = 0u;                 // col -1 halo
        if (l == 63) dn = 0u;                // col 128 halo
        c0[r] = __uint_as_float(wd << 16);          // col 2l
        c1[r] = __uint_as_float(wd & 0xFFFF0000u);  // col 2l+1
        cm1[r] = __uint_as_float(up & 0xFFFF0000u); // col 2l-1
        c2[r] = __uint_as_float(dn << 16);          // col 2l+2
      }
      // Y0 (even): kyA=1 row idx1 (q), kyB=3 row idx0 (q-1)
      acc[0] = fmaf(wp[5], c0[1], fmaf(wp[7], cm1[1],
               fmaf(wp[13], c0[0], fmaf(wp[15], cm1[0], acc[0]))));
      acc[1] = fmaf(wp[4], c1[1], fmaf(wp[6], c0[1],
               fmaf(wp[12], c1[0], fmaf(wp[14], c0[0], acc[1]))));
      acc[2] = fmaf(wp[5], c1[1], fmaf(wp[7], c0[1],
               fmaf(wp[13], c1[0], fmaf(wp[15], c0[0], acc[2]))));
      acc[3] = fmaf(wp[4], c2[1], fmaf(wp[6], c1[1],
               fmaf(wp[12], c2[0], fmaf(wp[14], c1[0], acc[3]))));
      // Y0+1 (odd): kyA=0 row idx2 (q+1), kyB=2 row idx1 (q)
      acc[4] = fmaf(wp[1], c0[2], fmaf(wp[3], cm1[2],
               fmaf(wp[9], c0[1], fmaf(wp[11], cm1[1], acc[4]))));
      acc[5] = fmaf(wp[0], c1[2], fmaf(wp[2], c0[2],
               fmaf(wp[8], c1[1], fmaf(wp[10], c0[1], acc[5]))));
      acc[6] = fmaf(wp[1], c1[2], fmaf(wp[3], c0[2],
               fmaf(wp[9], c1[1], fmaf(wp[11], c0[1], acc[6]))));
      acc[7] = fmaf(wp[0], c2[2], fmaf(wp[2], c1[2],
               fmaf(wp[8], c2[1], fmaf(wp[10], c1[1], acc[7]))));
    }
  }
  float bb = db1[0];
  f32x4 v0, v1;
#pragma unroll
  for (int c = 0; c < 4; ++c) {
    float u = acc[c] + bb;
    v0[c] = 1.f / (1.f + __expf(-u));
    float u2 = acc[4 + c] + bb;
    v1[c] = 1.f / (1.f + __expf(-u2));
  }
  long rbase = ((long)(b * 256 + Y0)) * 256 + 4 * l;
  *reinterpret_cast<f32x4*>(&rec[rbase]) = v0;
  *reinterpret_cast<f32x4*>(&rec[rbase + 256]) = v1;
}

// ---------------------------------------------------------------------------
extern "C" void kernel_launch(void* const* d_in, const int* in_sizes, int n_in,
                              void* d_out, int out_size, void* d_ws, size_t ws_size,
                              hipStream_t stream) {
  const float* x      = (const float*)d_in[0];
  const float* enc_w1 = (const float*)d_in[1];
  const float* enc_b1 = (const float*)d_in[2];
  const float* enc_w2 = (const float*)d_in[3];
  const float* enc_b2 = (const float*)d_in[4];
  const float* cb     = (const float*)d_in[5];
  const float* dec_w2 = (const float*)d_in[6];
  const float* dec_b2 = (const float*)d_in[7];
  const float* dec_w1 = (const float*)d_in[8];
  const float* dec_b1 = (const float*)d_in[9];

  float* out = (float*)d_out;
  float* ws  = (float*)d_ws;
  ushort_t* wCh  = (ushort_t*)ws;                   // 131072 ushort = 65536 f
  ushort_t* wCl  = (ushort_t*)(ws + 65536);
  ushort_t* wAh  = (ushort_t*)(ws + 131072);
  ushort_t* wAl  = (ushort_t*)(ws + 196608);
  ushort_t* cbFh = (ushort_t*)(ws + 262144);        // 32768 ushort = 16384 f
  ushort_t* cbFl = (ushort_t*)(ws + 278528);
  float* csqF = ws + 294912;                        // 8192 f
  float* dyn  = ws + 303104;                        // chunk buffers

  // Per-image: h_pk = 2,097,152 u32 (g bf16 aliases), z/q_pk = 262,144.
  const size_t PER_IMG = 2097152 + 262144;                   // 2,359,296 elems
  size_t avail = (ws_size / 4 > 303104 + 64) ? ws_size / 4 - 303104 - 64 : 0;
  int CB = 32;
  while (CB > 1 && (size_t)CB * PER_IMG > avail) CB >>= 1;

  zero_loss_k<<<dim3(1), 64, 0, stream>>>(out);
  repackA2_k<<<dim3(512), 256, 0, stream>>>(enc_w2, wCh, wCl);
  repackA_k<<<dim3(512), 256, 0, stream>>>(dec_w2, wAh, wAl);
  repackCB_k<<<dim3(128), 256, 0, stream>>>(cb, cbFh, cbFl);
  csqF_k<<<dim3(32), 256, 0, stream>>>(cb, csqF);

  for (int b0 = 0; b0 < 32; b0 += CB) {
    unsigned* hp = (unsigned*)dyn;                    // CB*2097152 (g aliases)
    float* zq = dyn + (size_t)CB * 2097152;           // CB*262144 (q_pk aliases)
    conv1_k<<<dim3(128, CB), 128, 0, stream>>>(
        x + (size_t)b0 * 65536, enc_w1, enc_b1, hp);
    conv2_k<<<dim3(32, CB), 512, 0, stream>>>(hp, wCh, wCl, enc_b2, zq);
    vq_k<<<dim3(CB * 64), 256, 0, stream>>>(
        zq, cb, cbFh, cbFl, csqF, (unsigned int*)zq, out, b0 * 4096);
    dconv2_k<<<dim3(64, CB), 512, 0, stream>>>(
        (const unsigned int*)zq, wAh, wAl, dec_b2, (ushort_t*)dyn /*g bf16*/);
    dconv1_k<<<dim3(32, CB), 256, 0, stream>>>(
        (const ushort_t*)dyn /*g*/, dec_w1, dec_b1,
        out + REC_OFF + (size_t)b0 * 65536);
  }
}

// Round 20
// 489.989 us; speedup vs baseline: 2.0399x; 1.0330x over previous
//
#include <hip/hip_runtime.h>
#include <math.h>

// ---------------------------------------------------------------------------
// VQ-VAE forward, bf16x3-MFMA for conv2, convT2 AND VQ distances.
//  x (32,1,256,256) -> [conv1 FUSED into conv2] -> z (f32) -> VQ -> q_pk
//  -> g (bf16 ushort) -> x_recon (32,1,256,256)
// d_out: [0]=vq_loss, [1..131072]=idx (as float), [131073..]=x_recon
// Fragment conventions (HW-verified, absmax 0.0 rounds 4-17):
//   A/B: lane l holds k_local = 8*(l>>4)+j, m/n = l&15
//   C/D: row = (l>>4)*4 + reg, col = l&15
// Round 20: conv1 fused into conv2 — h recomputed in-kernel (bit-identical
// FMA order -> identical packed bits), killing the 128MB h_pk write +
// 100MB readback per chunk. Threads 0..383 own (h-row, px-pair); x window
// in 24 regs; weights via wave-uniform s_load. conv1_k deleted.
// ---------------------------------------------------------------------------

#define REC_OFF 131073

typedef unsigned short ushort_t;
typedef __attribute__((ext_vector_type(8))) short bf16x8;
typedef __attribute__((ext_vector_type(4))) float f32x4;
typedef __attribute__((ext_vector_type(4))) unsigned int u32x4;
union FragU { u32x4 u; bf16x8 h; };

__device__ __forceinline__ unsigned pack_hilo(float v) {
  unsigned u = __float_as_uint(v);
  unsigned htop = u & 0xFFFF0000u;
  float rf = v - __uint_as_float(htop);
  return htop | (__float_as_uint(rf) >> 16);
}
__device__ __forceinline__ ushort_t bf16_rne(float v) {
  unsigned u = __float_as_uint(v);
  u += 0x7FFFu + ((u >> 16) & 1u);
  return (ushort_t)(u >> 16);
}

__global__ __launch_bounds__(64) void zero_loss_k(float* __restrict__ out) {
  if (threadIdx.x == 0) out[0] = 0.f;
}

// ---- conv2 A-table: [ks=ci0*4+ky][mt][lane][j] bf16 hi/lo -----------------
__global__ __launch_bounds__(256) void repackA2_k(
    const float* __restrict__ ew2,
    ushort_t* __restrict__ hi, ushort_t* __restrict__ lo) {
  int idx = blockIdx.x * 256 + threadIdx.x;        // 131072 total
  int j = idx & 7, l = (idx >> 3) & 63, mt = (idx >> 9) & 3, ks = idx >> 11;
  int ci = ((ks >> 2) << 3) + ((l >> 4) << 1) + (j >> 2);
  int ky = ks & 3, kx = j & 3, d = (mt << 4) + (l & 15);
  float val = ew2[((d << 7) + ci) * 16 + (ky << 2) + kx];
  unsigned u = __float_as_uint(val);
  float rf = val - __uint_as_float(u & 0xFFFF0000u);
  hi[idx] = (ushort_t)(u >> 16);
  lo[idx] = (ushort_t)(__float_as_uint(rf) >> 16);
}

// ---- dconv2 A-table (proven) ----------------------------------------------
__global__ __launch_bounds__(256) void repackA_k(
    const float* __restrict__ dw2,   // dec_w2 (ci=64, co=128, ky, kx)
    ushort_t* __restrict__ hi, ushort_t* __restrict__ lo) {
  int idx = blockIdx.x * 256 + threadIdx.x;        // 131072 total
  int j = idx & 7, l = (idx >> 3) & 63, mt = (idx >> 9) & 7;
  int s = (idx >> 12) & 7, v = idx >> 15;
  int co = (mt << 4) + (l & 15);
  int ci = (s << 3) + ((l >> 4) << 1) + (j >> 2);
  int tap = j & 3;
  int Yp = v >> 1, pX = v & 1;
  int kyA = 1 - Yp, kyB = kyA + 2;
  int kxA = pX ? 0 : 1, kxB = kxA + 2;
  int ky = (tap & 2) ? kyB : kyA;
  int kx = (tap & 1) ? kxA : kxB;
  float val = dw2[(((ci << 7) + co) << 4) + (ky << 2) + kx];
  unsigned u = __float_as_uint(val);
  float rf = val - __uint_as_float(u & 0xFFFF0000u);
  hi[idx] = (ushort_t)(u >> 16);
  lo[idx] = (ushort_t)(__float_as_uint(rf) >> 16);
}

// ---- VQ codebook A-table: [ks(2)][mt(32)][lane(64)][j(8)] bf16 hi/lo ------
__global__ __launch_bounds__(256) void repackCB_k(
    const float* __restrict__ cb,
    ushort_t* __restrict__ hi, ushort_t* __restrict__ lo) {
  int idx = blockIdx.x * 256 + threadIdx.x;        // 32768 total
  int j = idx & 7, l = (idx >> 3) & 63, mt = (idx >> 9) & 31, ks = idx >> 14;
  int code = (mt << 4) + (l & 15);
  int k = (ks << 5) + ((l >> 4) << 3) + j;
  float val = cb[(code << 6) + k];
  unsigned u = __float_as_uint(val);
  float rf = val - __uint_as_float(u & 0xFFFF0000u);
  hi[idx] = (ushort_t)(u >> 16);
  lo[idx] = (ushort_t)(__float_as_uint(rf) >> 16);
}

// ---- csq in C/D fragment order: csqF[(mt*64+l)*4+r] = |cb[code]|^2 --------
__global__ __launch_bounds__(256) void csqF_k(
    const float* __restrict__ cb, float* __restrict__ csqF) {
  int idx = blockIdx.x * 256 + threadIdx.x;        // 8192 total
  int r = idx & 3, l = (idx >> 2) & 63, mt = idx >> 8;
  int code = (mt << 4) + ((l >> 4) << 2) + r;
  const float* cp = cb + (code << 6);
  float s = 0.f;
#pragma unroll
  for (int d = 0; d < 64; ++d) s = fmaf(cp[d], cp[d], s);
  csqF[idx] = s;
}

// ---------------- fused conv1+conv2 + relu: bf16x3 MFMA ---------------------
// 2 z-rows/block, 512 thr = 8 waves (Yloc=w>>2, mtg=(w>>1)&1, ntg=w&1),
// LDS double-buffered. Staging REPLACED by in-kernel conv1: threads 0..383
// own (h-row row=t>>6 in 0..5, px-pair p=t&63); per rnd compute 16 h values
// (8 ci x 2 px) from x window in regs, FMA order identical to old conv1_k.
#define C2RL 133
__device__ __forceinline__ void compute_h8(
    unsigned (*hb)[6][C2RL], int rnd, const float (&xr)[4][6],
    int row, int p, bool vh, bool active,
    const float* __restrict__ ew1, const float* __restrict__ eb1) {
  if (!active) return;
#pragma unroll
  for (int ci = 0; ci < 8; ++ci) {
    int c8 = (rnd << 3) + ci;
    const float* wp = ew1 + (c8 << 4);             // wave-uniform -> s_load
    float bias = eb1[c8];
#pragma unroll
    for (int e = 0; e < 2; ++e) {
      float acc = bias;
#pragma unroll
      for (int ky = 0; ky < 4; ++ky)
#pragma unroll
        for (int kx = 0; kx < 4; ++kx)
          acc = fmaf(xr[ky][2 * e + kx], wp[ky * 4 + kx], acc);
      hb[ci][row][1 + 2 * p + e] = vh ? pack_hilo(fmaxf(acc, 0.f)) : 0u;
    }
  }
}

__global__ __launch_bounds__(512) void conv2_k(
    const float* __restrict__ xin,  // pre-offset to chunk base
    const float* __restrict__ ew1, const float* __restrict__ eb1,
    const ushort_t* __restrict__ wCh, const ushort_t* __restrict__ wCl,
    const float* __restrict__ b2, float* __restrict__ z) {
  __shared__ unsigned hs[2][8][6][C2RL];           // 51,072 B
  int a = blockIdx.x, b = blockIdx.y;              // outputs y = 2a, 2a+1
  int t = threadIdx.x, l = t & 63;
  int w = __builtin_amdgcn_readfirstlane(t >> 6);  // 0..7
  int Yloc = w >> 2, mtg = (w >> 1) & 1, ntg = w & 1;
  int y = 2 * a + Yloc;
  int g = l >> 4;

  if (t < 48) {                                    // x-halo prezero, both bufs
    int ci = t & 7, r = t >> 3;                    // r in 0..5
    hs[0][ci][r][0] = 0u;
    hs[0][ci][r][129] = 0u;
    hs[1][ci][r][0] = 0u;
    hs[1][ci][r][129] = 0u;
  }

  // conv1 thread mapping: row = t>>6 (0..5 active), px pair p = t&63.
  int row = t >> 6, p = t & 63;
  bool hactive = row < 6;
  int hy = 4 * a - 1 + row;
  bool vh = hy >= 0 && hy < 128;
  const float* xb = xin + ((long)b << 16);
  float xr[4][6];
#pragma unroll
  for (int r = 0; r < 4; ++r)
#pragma unroll
    for (int c = 0; c < 6; ++c) xr[r][c] = 0.f;
  if (hactive) {
#pragma unroll
    for (int r = 0; r < 4; ++r) {
      int gy = 8 * a - 3 + 2 * row + r;
      bool oky = gy >= 0 && gy < 256;
#pragma unroll
      for (int c = 0; c < 6; ++c) {
        int gx = 4 * p - 1 + c;
        bool okx = gx >= 0 && gx < 256;
        xr[r][c] = (oky && okx) ? xb[(gy << 8) + gx] : 0.f;
      }
    }
  }

  compute_h8(hs[0], 0, xr, row, p, vh, hactive, ew1, eb1);
  __syncthreads();

  f32x4 acc[2][2];
#pragma unroll
  for (int ml = 0; ml < 2; ++ml)
#pragma unroll
    for (int nl = 0; nl < 2; ++nl) acc[ml][nl] = (f32x4)0.f;

  for (int rnd = 0; rnd < 16; ++rnd) {
    int cur = rnd & 1;
#pragma unroll
    for (int ky = 0; ky < 4; ++ky) {
      int ks = (rnd << 2) + ky;
      int lrow = 2 * Yloc + ky;                    // LDS row 0..5
      FragU ah[2], al_[2];
#pragma unroll
      for (int ml = 0; ml < 2; ++ml) {
        int mt = (mtg << 1) + ml;
        long aoff = (((long)ks * 4 + mt) * 64 + l) * 8;
        ah[ml].u = *reinterpret_cast<const u32x4*>(wCh + aoff);
        al_[ml].u = *reinterpret_cast<const u32x4*>(wCl + aoff);
      }
#pragma unroll
      for (int nl = 0; nl < 2; ++nl) {
        int nt = (ntg << 1) + nl;
        const unsigned* pa = &hs[cur][g * 2][lrow][(nt << 5) + 2 * (l & 15)];
        const unsigned* pb = &hs[cur][g * 2 + 1][lrow][(nt << 5) + 2 * (l & 15)];
        unsigned a0 = pa[0], a1 = pa[1], a2 = pa[2], a3 = pa[3];
        unsigned b0 = pb[0], b1 = pb[1], b2_ = pb[2], b3 = pb[3];
        FragU bh, bl;
        bh.u[0] = __builtin_amdgcn_perm(a1, a0, 0x07060302u);
        bl.u[0] = __builtin_amdgcn_perm(a1, a0, 0x05040100u);
        bh.u[1] = __builtin_amdgcn_perm(a3, a2, 0x07060302u);
        bl.u[1] = __builtin_amdgcn_perm(a3, a2, 0x05040100u);
        bh.u[2] = __builtin_amdgcn_perm(b1, b0, 0x07060302u);
        bl.u[2] = __builtin_amdgcn_perm(b1, b0, 0x05040100u);
        bh.u[3] = __builtin_amdgcn_perm(b3, b2_, 0x07060302u);
        bl.u[3] = __builtin_amdgcn_perm(b3, b2_, 0x05040100u);
#pragma unroll
        for (int ml = 0; ml < 2; ++ml) {
          acc[ml][nl] = __builtin_amdgcn_mfma_f32_16x16x32_bf16(
              ah[ml].h, bh.h, acc[ml][nl], 0, 0, 0);
          acc[ml][nl] = __builtin_amdgcn_mfma_f32_16x16x32_bf16(
              ah[ml].h, bl.h, acc[ml][nl], 0, 0, 0);
          acc[ml][nl] = __builtin_amdgcn_mfma_f32_16x16x32_bf16(
              al_[ml].h, bh.h, acc[ml][nl], 0, 0, 0);
        }
      }
    }
    if (rnd < 15) {                                // compute next tile -> buf^1
      compute_h8(hs[cur ^ 1], rnd + 1, xr, row, p, vh, hactive, ew1, eb1);
      __syncthreads();                             // next buf visible; cur free
    }
  }
#pragma unroll
  for (int ml = 0; ml < 2; ++ml) {
#pragma unroll
    for (int nl = 0; nl < 2; ++nl) {
#pragma unroll
      for (int r = 0; r < 4; ++r) {
        int d = (((mtg << 1) + ml) << 4) + (g << 2) + r;
        int x = (((ntg << 1) + nl) << 4) + (l & 15);
        float v = fmaxf(acc[ml][nl][r] + b2[d], 0.f);
        z[((b * 64 + d) * 64 + y) * 64 + x] = v;
      }
    }
  }
}

// ---------------- VQ: bf16x3 MFMA distances + fp32 argmin (chunked) ---------
__global__ __launch_bounds__(256) void vq_k(
    const float* z, const float* __restrict__ cb,
    const ushort_t* __restrict__ cbFh, const ushort_t* __restrict__ cbFl,
    const float* __restrict__ csqF, unsigned int* q_pk,
    float* __restrict__ out, int n0) {
  __shared__ unsigned zS[64 * 67];                 // 17.2 KB
  __shared__ int bk_arr[64];
  __shared__ float redl[4];
  int t = threadIdx.x, l = t & 63;
  int w = __builtin_amdgcn_readfirstlane(t >> 6);
  int nbase = blockIdx.x * 64;
  int b = nbase >> 12, y = (nbase >> 6) & 63;
  long zbase = (long)b * 262144 + y * 64;

  float zv[16];
#pragma unroll
  for (int j = 0; j < 16; ++j) {
    zv[j] = z[zbase + (long)((w << 4) + j) * 4096 + l];
    zS[l * 67 + (w << 4) + j] = pack_hilo(zv[j]);
  }
  __syncthreads();

  int pp = (w << 4) + (l & 15);
  FragU bh[2], bl[2];
#pragma unroll
  for (int ks = 0; ks < 2; ++ks) {
    const unsigned* zp = &zS[pp * 67 + (ks << 5) + ((l >> 4) << 3)];
    unsigned u0 = zp[0], u1 = zp[1], u2 = zp[2], u3 = zp[3];
    unsigned u4 = zp[4], u5 = zp[5], u6 = zp[6], u7 = zp[7];
    bh[ks].u[0] = __builtin_amdgcn_perm(u1, u0, 0x07060302u);
    bl[ks].u[0] = __builtin_amdgcn_perm(u1, u0, 0x05040100u);
    bh[ks].u[1] = __builtin_amdgcn_perm(u3, u2, 0x07060302u);
    bl[ks].u[1] = __builtin_amdgcn_perm(u3, u2, 0x05040100u);
    bh[ks].u[2] = __builtin_amdgcn_perm(u5, u4, 0x07060302u);
    bl[ks].u[2] = __builtin_amdgcn_perm(u5, u4, 0x05040100u);
    bh[ks].u[3] = __builtin_amdgcn_perm(u7, u6, 0x07060302u);
    bl[ks].u[3] = __builtin_amdgcn_perm(u7, u6, 0x05040100u);
  }

  int g = l >> 4;
  float bd = 1e30f;
  int bk = 0;
  for (int mc = 0; mc < 4; ++mc) {                 // 128 codes per chunk
    f32x4 acc[8];
#pragma unroll
    for (int m8 = 0; m8 < 8; ++m8) acc[m8] = (f32x4)0.f;
#pragma unroll
    for (int ks = 0; ks < 2; ++ks) {
#pragma unroll
      for (int m8 = 0; m8 < 8; ++m8) {
        long aoff = (((long)(ks * 32 + mc * 8 + m8) * 64) + l) * 8;
        FragU ah, al_;
        ah.u = *reinterpret_cast<const u32x4*>(cbFh + aoff);
        al_.u = *reinterpret_cast<const u32x4*>(cbFl + aoff);
        acc[m8] = __builtin_amdgcn_mfma_f32_16x16x32_bf16(
            ah.h, bh[ks].h, acc[m8], 0, 0, 0);
        acc[m8] = __builtin_amdgcn_mfma_f32_16x16x32_bf16(
            ah.h, bl[ks].h, acc[m8], 0, 0, 0);
        acc[m8] = __builtin_amdgcn_mfma_f32_16x16x32_bf16(
            al_.h, bh[ks].h, acc[m8], 0, 0, 0);
      }
    }
#pragma unroll
    for (int m8 = 0; m8 < 8; ++m8) {
      int mt = mc * 8 + m8;
      f32x4 cq = *reinterpret_cast<const f32x4*>(csqF + ((mt << 6) + l) * 4);
#pragma unroll
      for (int r = 0; r < 4; ++r) {
        float d = fmaf(-2.f, acc[m8][r], cq[r]);
        if (d < bd) { bd = d; bk = (mt << 4) + (g << 2) + r; }
      }
    }
  }
#pragma unroll
  for (int m = 16; m <= 32; m <<= 1) {
    float d2 = __shfl_xor(bd, m);
    int k2 = __shfl_xor(bk, m);
    if (d2 < bd || (d2 == bd && k2 < bk)) { bd = d2; bk = k2; }
  }
  if (l < 16) {
    bk_arr[(w << 4) + l] = bk;
    out[1 + n0 + nbase + (w << 4) + l] = (float)bk;
  }
  __syncthreads();

  int bkp = bk_arr[l];
  const float* cbest = cb + (bkp << 6) + (w << 4);
  float ls = 0.f;
#pragma unroll
  for (int j = 0; j < 16; ++j) {
    float c = cbest[j];
    q_pk[zbase + (long)((w << 4) + j) * 4096 + l] = pack_hilo(c);
    float df = c - zv[j];
    ls = fmaf(df, df, ls);
  }
#pragma unroll
  for (int m = 32; m; m >>= 1) ls += __shfl_xor(ls, m);
  if (l == 0) redl[w] = ls;
  __syncthreads();
  if (t == 0)
    atomicAdd(out, (redl[0] + redl[1] + redl[2] + redl[3]) * (1.25f / 8388608.f));
}

// ---------------- convT2 (64->128, 4x4, s2, p1) + relu: bf16x3 MFMA ---------
// 2 Y-rows per block, 512 thr = 8 waves (round 14); g stored as bf16 (RNE).
__global__ __launch_bounds__(512) void dconv2_k(
    const unsigned int* __restrict__ q_pk, const ushort_t* __restrict__ wAh,
    const ushort_t* __restrict__ wAl, const float* __restrict__ db2,
    ushort_t* __restrict__ gp) {
  __shared__ unsigned int rows[64][3][68];         // 52,224 B
  int a = blockIdx.x, b = blockIdx.y;              // Y0 = 2a
  int t = threadIdx.x, l = t & 63;
  int w = __builtin_amdgcn_readfirstlane(t >> 6);  // 0..7
  int Yloc = w >> 2, pX = w & 1, coh = (w >> 1) & 1;
  int Y = 2 * a + Yloc;
  int v = (Yloc << 1) | pX;                        // = ((Y&1)<<1)|pX
  int rA = Yloc + 1, rB = Yloc;                    // LDS row idx: yA, yB

  if (t < 192) {
    int ci = t & 63, r = t >> 6;
    rows[ci][r][0] = 0u;
    rows[ci][r][65] = 0u;
  }
  long qb = (long)b * 262144;
#pragma unroll
  for (int r = 0; r < 3; ++r) {
    int yr = a - 1 + r;
    bool ok = (yr >= 0) && (yr < 64);
    for (int s = t; s < 1024; s += 512) {          // 2 iters
      int ci = s >> 4, c4 = s & 15;
      u32x4 val = ok ? *reinterpret_cast<const u32x4*>(
                           q_pk + qb + ci * 4096 + yr * 64 + (c4 << 2))
                     : (u32x4)0u;
      unsigned* dst = &rows[ci][r][1 + (c4 << 2)];
      dst[0] = val[0]; dst[1] = val[1]; dst[2] = val[2]; dst[3] = val[3];
    }
  }
  __syncthreads();

  f32x4 acc[4][4];
#pragma unroll
  for (int mt = 0; mt < 4; ++mt)
#pragma unroll
    for (int nt = 0; nt < 4; ++nt) acc[mt][nt] = (f32x4)0.f;

  for (int s8 = 0; s8 < 8; ++s8) {
    FragU ah[4], al[4];
#pragma unroll
    for (int mt = 0; mt < 4; ++mt) {
      long off = ((((long)(v * 8 + s8) * 8 + (coh * 4 + mt)) * 64 + l) * 8);
      ah[mt].u = *reinterpret_cast<const u32x4*>(wAh + off);
      al[mt].u = *reinterpret_cast<const u32x4*>(wAl + off);
    }
#pragma unroll
    for (int nt = 0; nt < 4; ++nt) {
      int p = nt * 16 + (l & 15) + pX;
      int cc0 = (s8 << 3) + ((l >> 4) << 1);
      unsigned u0 = rows[cc0][rA][p], u1 = rows[cc0][rA][p + 1];
      unsigned u2 = rows[cc0][rB][p], u3 = rows[cc0][rB][p + 1];
      unsigned u4 = rows[cc0 + 1][rA][p], u5 = rows[cc0 + 1][rA][p + 1];
      unsigned u6 = rows[cc0 + 1][rB][p], u7 = rows[cc0 + 1][rB][p + 1];
      FragU bh, bl;
      bh.u[0] = (u0 >> 16) | (u1 & 0xFFFF0000u);
      bl.u[0] = (u0 & 0xFFFFu) | (u1 << 16);
      bh.u[1] = (u2 >> 16) | (u3 & 0xFFFF0000u);
      bl.u[1] = (u2 & 0xFFFFu) | (u3 << 16);
      bh.u[2] = (u4 >> 16) | (u5 & 0xFFFF0000u);
      bl.u[2] = (u4 & 0xFFFFu) | (u5 << 16);
      bh.u[3] = (u6 >> 16) | (u7 & 0xFFFF0000u);
      bl.u[3] = (u6 & 0xFFFFu) | (u7 << 16);
#pragma unroll
      for (int mt = 0; mt < 4; ++mt) {
        acc[mt][nt] = __builtin_amdgcn_mfma_f32_16x16x32_bf16(
            ah[mt].h, bh.h, acc[mt][nt], 0, 0, 0);
        acc[mt][nt] = __builtin_amdgcn_mfma_f32_16x16x32_bf16(
            ah[mt].h, bl.h, acc[mt][nt], 0, 0, 0);
        acc[mt][nt] = __builtin_amdgcn_mfma_f32_16x16x32_bf16(
            al[mt].h, bh.h, acc[mt][nt], 0, 0, 0);
      }
    }
  }

#pragma unroll
  for (int mt = 0; mt < 4; ++mt) {
#pragma unroll
    for (int r = 0; r < 4; ++r) {
      int co = ((coh * 4 + mt) << 4) + ((l >> 4) << 2) + r;
      float bias = db2[co];
#pragma unroll
      for (int nt = 0; nt < 4; ++nt) {
        int X = ((nt << 4) + (l & 15)) * 2 + pX;
        float val = fmaxf(acc[mt][nt][r] + bias, 0.f);
        gp[((b * 128 + co) * 128 + Y) * 128 + X] = bf16_rne(val);
      }
    }
  }
}

// ---------------- convT1 (128->1, 4x4, s2, p1) + sigmoid --------------------
// bf16 g via u32 word loads + shfl neighbors (proven round 19).
__global__ __launch_bounds__(256) void dconv1_k(
    const ushort_t* __restrict__ g, const float* __restrict__ wd1,
    const float* __restrict__ db1, float* __restrict__ rec) {
  int a = blockIdx.x, b = blockIdx.y;
  int t = threadIdx.x, l = t & 63;
  int w = __builtin_amdgcn_readfirstlane(t >> 6);
  int q = 4 * a + w;                         // input row center; rows q-1,q,q+1
  int Y0 = 8 * a + 2 * w;
  bool ok0 = q >= 1;                         // row q-1 valid
  bool ok2 = q <= 126;                       // row q+1 valid
  const unsigned* gw = (const unsigned*)g;
  long cbase = (long)b * 128;

  float acc[8] = {0.f, 0.f, 0.f, 0.f, 0.f, 0.f, 0.f, 0.f};

  for (int ci = 0; ci < 128; ci += 2) {
    long i0 = (cbase + ci) * 128;            // row-index base (x128 rows)
    long i1 = i0 + 128;
    unsigned wa[3], wb[3];
    wa[0] = ok0 ? gw[(i0 + q - 1) * 64 + l] : 0u;
    wa[1] = gw[(i0 + q) * 64 + l];
    wa[2] = ok2 ? gw[(i0 + q + 1) * 64 + l] : 0u;
    wb[0] = ok0 ? gw[(i1 + q - 1) * 64 + l] : 0u;
    wb[1] = gw[(i1 + q) * 64 + l];
    wb[2] = ok2 ? gw[(i1 + q + 1) * 64 + l] : 0u;

    const float* wp0 = wd1 + ci * 16;        // wave-uniform -> s_load
    const float* wp1 = wp0 + 16;
#pragma unroll
    for (int h = 0; h < 2; ++h) {
      const unsigned* wrd = h ? wb : wa;
      const float* wp = h ? wp1 : wp0;
      float cm1[3], c0[3], c1[3], c2[3];
#pragma unroll
      for (int r = 0; r < 3; ++r) {
        unsigned wd = wrd[r];
        unsigned up = __shfl_up(wd, 1);      // lane l-1's word
        unsigned dn = __shfl_down(wd, 1);    // lane l+1's word
        if (l == 0) up = 0u;                 // col -1 halo
        if (l == 63) dn = 0u;                // col 128 halo
        c0[r] = __uint_as_float(wd << 16);          // col 2l
        c1[r] = __uint_as_float(wd & 0xFFFF0000u);  // col 2l+1
        cm1[r] = __uint_as_float(up & 0xFFFF0000u); // col 2l-1
        c2[r] = __uint_as_float(dn << 16);          // col 2l+2
      }
      // Y0 (even): kyA=1 row idx1 (q), kyB=3 row idx0 (q-1)
      acc[0] = fmaf(wp[5], c0[1], fmaf(wp[7], cm1[1],
               fmaf(wp[13], c0[0], fmaf(wp[15], cm1[0], acc[0]))));
      acc[1] = fmaf(wp[4], c1[1], fmaf(wp[6], c0[1],
               fmaf(wp[12], c1[0], fmaf(wp[14], c0[0], acc[1]))));
      acc[2] = fmaf(wp[5], c1[1], fmaf(wp[7], c0[1],
               fmaf(wp[13], c1[0], fmaf(wp[15], c0[0], acc[2]))));
      acc[3] = fmaf(wp[4], c2[1], fmaf(wp[6], c1[1],
               fmaf(wp[12], c2[0], fmaf(wp[14], c1[0], acc[3]))));
      // Y0+1 (odd): kyA=0 row idx2 (q+1), kyB=2 row idx1 (q)
      acc[4] = fmaf(wp[1], c0[2], fmaf(wp[3], cm1[2],
               fmaf(wp[9], c0[1], fmaf(wp[11], cm1[1], acc[4]))));
      acc[5] = fmaf(wp[0], c1[2], fmaf(wp[2], c0[2],
               fmaf(wp[8], c1[1], fmaf(wp[10], c0[1], acc[5]))));
      acc[6] = fmaf(wp[1], c1[2], fmaf(wp[3], c0[2],
               fmaf(wp[9], c1[1], fmaf(wp[11], c0[1], acc[6]))));
      acc[7] = fmaf(wp[0], c2[2], fmaf(wp[2], c1[2],
               fmaf(wp[8], c2[1], fmaf(wp[10], c1[1], acc[7]))));
    }
  }
  float bb = db1[0];
  f32x4 v0, v1;
#pragma unroll
  for (int c = 0; c < 4; ++c) {
    float u = acc[c] + bb;
    v0[c] = 1.f / (1.f + __expf(-u));
    float u2 = acc[4 + c] + bb;
    v1[c] = 1.f / (1.f + __expf(-u2));
  }
  long rbase = ((long)(b * 256 + Y0)) * 256 + 4 * l;
  *reinterpret_cast<f32x4*>(&rec[rbase]) = v0;
  *reinterpret_cast<f32x4*>(&rec[rbase + 256]) = v1;
}

// ---------------------------------------------------------------------------
extern "C" void kernel_launch(void* const* d_in, const int* in_sizes, int n_in,
                              void* d_out, int out_size, void* d_ws, size_t ws_size,
                              hipStream_t stream) {
  const float* x      = (const float*)d_in[0];
  const float* enc_w1 = (const float*)d_in[1];
  const float* enc_b1 = (const float*)d_in[2];
  const float* enc_w2 = (const float*)d_in[3];
  const float* enc_b2 = (const float*)d_in[4];
  const float* cb     = (const float*)d_in[5];
  const float* dec_w2 = (const float*)d_in[6];
  const float* dec_b2 = (const float*)d_in[7];
  const float* dec_w1 = (const float*)d_in[8];
  const float* dec_b1 = (const float*)d_in[9];

  float* out = (float*)d_out;
  float* ws  = (float*)d_ws;
  ushort_t* wCh  = (ushort_t*)ws;                   // 131072 ushort = 65536 f
  ushort_t* wCl  = (ushort_t*)(ws + 65536);
  ushort_t* wAh  = (ushort_t*)(ws + 131072);
  ushort_t* wAl  = (ushort_t*)(ws + 196608);
  ushort_t* cbFh = (ushort_t*)(ws + 262144);        // 32768 ushort = 16384 f
  ushort_t* cbFl = (ushort_t*)(ws + 278528);
  float* csqF = ws + 294912;                        // 8192 f
  float* dyn  = ws + 303104;                        // chunk buffers

  // Per-image: g bf16 = 2,097,152 ushort (1/4 of old slot), z/q_pk = 262,144.
  const size_t PER_IMG = 2097152 + 262144;          // keep proven layout
  size_t avail = (ws_size / 4 > 303104 + 64) ? ws_size / 4 - 303104 - 64 : 0;
  int CB = 32;
  while (CB > 1 && (size_t)CB * PER_IMG > avail) CB >>= 1;

  zero_loss_k<<<dim3(1), 64, 0, stream>>>(out);
  repackA2_k<<<dim3(512), 256, 0, stream>>>(enc_w2, wCh, wCl);
  repackA_k<<<dim3(512), 256, 0, stream>>>(dec_w2, wAh, wAl);
  repackCB_k<<<dim3(128), 256, 0, stream>>>(cb, cbFh, cbFl);
  csqF_k<<<dim3(32), 256, 0, stream>>>(cb, csqF);

  for (int b0 = 0; b0 < 32; b0 += CB) {
    float* zq = dyn + (size_t)CB * 2097152;           // CB*262144 (q_pk aliases)
    conv2_k<<<dim3(32, CB), 512, 0, stream>>>(
        x + (size_t)b0 * 65536, enc_w1, enc_b1, wCh, wCl, enc_b2, zq);
    vq_k<<<dim3(CB * 64), 256, 0, stream>>>(
        zq, cb, cbFh, cbFl, csqF, (unsigned int*)zq, out, b0 * 4096);
    dconv2_k<<<dim3(64, CB), 512, 0, stream>>>(
        (const unsigned int*)zq, wAh, wAl, dec_b2, (ushort_t*)dyn /*g bf16*/);
    dconv1_k<<<dim3(32, CB), 256, 0, stream>>>(
        (const ushort_t*)dyn /*g*/, dec_w1, dec_b1,
        out + REC_OFF + (size_t)b0 * 65536);
  }
}